// Round 1
// baseline (78.986 us; speedup 1.0000x reference)
//
#include <hip/hip_runtime.h>

#define N 4096
#define D_OBS 64
#define D_ENC 128

typedef short short8 __attribute__((ext_vector_type(8)));
typedef float f32x4 __attribute__((ext_vector_type(4)));

__device__ __forceinline__ unsigned short f2bf(float x) {
    union { float f; unsigned u; } v; v.f = x;
    unsigned r = v.u + 0x7fffu + ((v.u >> 16) & 1u);   // RNE
    return (unsigned short)(r >> 16);
}

// Kernel 1: one wave per row. bf16 conversion + fp32 row norms / row sums.
__global__ void prep_kernel(const float* __restrict__ obs, const float* __restrict__ enc,
                            unsigned short* __restrict__ obs_bf, unsigned short* __restrict__ enc_bf,
                            float* __restrict__ obs_nrm, float* __restrict__ obs_sum,
                            float* __restrict__ enc_nrm, float* __restrict__ enc_sum,
                            float* __restrict__ out) {
    int tid  = threadIdx.x;
    int lane = tid & 63;
    int row  = blockIdx.x * 4 + (tid >> 6);
    if (blockIdx.x == 0 && tid == 0) out[0] = 0.0f;

    float o  = obs[row * D_OBS + lane];
    float e0 = enc[row * D_ENC + lane];
    float e1 = enc[row * D_ENC + 64 + lane];
    obs_bf[row * D_OBS + lane]      = f2bf(o);
    enc_bf[row * D_ENC + lane]      = f2bf(e0);
    enc_bf[row * D_ENC + 64 + lane] = f2bf(e1);

    float so = o,        no = o * o;
    float se = e0 + e1,  ne = e0 * e0 + e1 * e1;
    #pragma unroll
    for (int m = 32; m >= 1; m >>= 1) {
        so += __shfl_xor(so, m);
        no += __shfl_xor(no, m);
        se += __shfl_xor(se, m);
        ne += __shfl_xor(ne, m);
    }
    if (lane == 0) {
        obs_sum[row] = so; obs_nrm[row] = no;
        enc_sum[row] = se; enc_nrm[row] = ne;
    }
}

// Kernel 2: one wave per 64x64 pair tile. Dual gram (obs K=64, enc K=128) via
// mfma_f32_16x16x32_bf16, fused epilogue, wave reduce, one atomic per block.
__global__ __launch_bounds__(64) void pair_kernel(
    const unsigned short* __restrict__ obs_bf, const unsigned short* __restrict__ enc_bf,
    const float* __restrict__ obs_nrm, const float* __restrict__ obs_sum,
    const float* __restrict__ enc_nrm, const float* __restrict__ enc_sum,
    float* __restrict__ out)
{
    const float EPSV   = 1e-6f;
    const float floorO = (float)D_OBS * 1e-12f;   // 6.4e-11
    const float floorE = (float)D_ENC * 1e-12f;   // 1.28e-10

    int l  = threadIdx.x;
    int bi = blockIdx.x & 63, bj = blockIdx.x >> 6;
    int I0 = bi * 64, J0 = bj * 64;
    int lr = l & 15;           // fragment row/col within 16
    int lk = (l >> 4) * 8;     // k offset within 32-K step

    const unsigned short* aObs = obs_bf + (size_t)(I0 + lr) * D_OBS + lk;
    const unsigned short* bObs = obs_bf + (size_t)(J0 + lr) * D_OBS + lk;
    const unsigned short* aEnc = enc_bf + (size_t)(I0 + lr) * D_ENC + lk;
    const unsigned short* bEnc = enc_bf + (size_t)(J0 + lr) * D_ENC + lk;

    f32x4 accO[4][4], accE[4][4];
    #pragma unroll
    for (int r = 0; r < 4; r++)
        #pragma unroll
        for (int c = 0; c < 4; c++) {
            accO[r][c] = (f32x4){0.f, 0.f, 0.f, 0.f};
            accE[r][c] = (f32x4){0.f, 0.f, 0.f, 0.f};
        }

    #pragma unroll
    for (int ks = 0; ks < 2; ks++) {               // obs gram, K=64
        short8 a[4], b[4];
        #pragma unroll
        for (int r = 0; r < 4; r++) a[r] = *(const short8*)(aObs + r * 16 * D_OBS + ks * 32);
        #pragma unroll
        for (int c = 0; c < 4; c++) b[c] = *(const short8*)(bObs + c * 16 * D_OBS + ks * 32);
        #pragma unroll
        for (int r = 0; r < 4; r++)
            #pragma unroll
            for (int c = 0; c < 4; c++)
                accO[r][c] = __builtin_amdgcn_mfma_f32_16x16x32_bf16(a[r], b[c], accO[r][c], 0, 0, 0);
    }
    #pragma unroll
    for (int ks = 0; ks < 4; ks++) {               // enc gram, K=128
        short8 a[4], b[4];
        #pragma unroll
        for (int r = 0; r < 4; r++) a[r] = *(const short8*)(aEnc + r * 16 * D_ENC + ks * 32);
        #pragma unroll
        for (int c = 0; c < 4; c++) b[c] = *(const short8*)(bEnc + c * 16 * D_ENC + ks * 32);
        #pragma unroll
        for (int r = 0; r < 4; r++)
            #pragma unroll
            for (int c = 0; c < 4; c++)
                accE[r][c] = __builtin_amdgcn_mfma_f32_16x16x32_bf16(a[r], b[c], accE[r][c], 0, 0, 0);
    }

    // j-side norms preload (4 per array, indexed by cb)
    float jn_no[4], jn_so[4], jn_ne[4], jn_se[4];
    #pragma unroll
    for (int c = 0; c < 4; c++) {
        int j = J0 + c * 16 + lr;
        jn_no[c] = obs_nrm[j]; jn_so[c] = obs_sum[j];
        jn_ne[c] = enc_nrm[j]; jn_se[c] = enc_sum[j];
    }

    float lsum = 0.0f;
    int rq = (l >> 4) * 4;
    #pragma unroll
    for (int r = 0; r < 4; r++) {
        #pragma unroll
        for (int q = 0; q < 4; q++) {
            int i = I0 + r * 16 + rq + q;
            float no_i = obs_nrm[i], so_i = obs_sum[i];
            float ne_i = enc_nrm[i], se_i = enc_sum[i];
            #pragma unroll
            for (int c = 0; c < 4; c++) {
                int j = J0 + c * 16 + lr;
                float dob = accO[r][c][q];
                float den = accE[r][c][q];
                // obs squared distance (clamped) -> negative mask
                float sqo = no_i + jn_no[c] - 2.0f * dob
                          + 2.0f * EPSV * (so_i - jn_so[c]) + floorO;
                sqo = fmaxf(sqo, floorO);
                bool neg = sqo > 1e-4f;            // obs_dist > 0.01
                // enc distance
                float sqe = ne_i + jn_ne[c] - 2.0f * den
                          + 2.0f * EPSV * (se_i - jn_se[c]) + floorE;
                float de = sqrtf(fmaxf(sqe, floorE));
                float contrib = neg ? fmaxf(1.0f - de, 0.0f) : (1.0f + de);
                if (i == j) contrib = 1.0f + 1.13137085e-05f;  // exact: 1 + EPS*sqrt(128)
                lsum += contrib;
            }
        }
    }

    #pragma unroll
    for (int m = 32; m >= 1; m >>= 1) lsum += __shfl_xor(lsum, m);
    if (l == 0) atomicAdd(out, lsum * (1.0f / 16777216.0f));   // /N^2, exact pow2 scale
}

extern "C" void kernel_launch(void* const* d_in, const int* in_sizes, int n_in,
                              void* d_out, int out_size, void* d_ws, size_t ws_size,
                              hipStream_t stream) {
    const float* obs = (const float*)d_in[0];
    const float* enc = (const float*)d_in[1];
    float* out = (float*)d_out;

    char* ws = (char*)d_ws;
    unsigned short* obs_bf = (unsigned short*)(ws + 0);          // 4096*64*2  = 512 KiB
    unsigned short* enc_bf = (unsigned short*)(ws + 524288);     // 4096*128*2 = 1 MiB
    float* obs_nrm = (float*)(ws + 1572864);
    float* obs_sum = (float*)(ws + 1589248);
    float* enc_nrm = (float*)(ws + 1605632);
    float* enc_sum = (float*)(ws + 1622016);

    prep_kernel<<<1024, 256, 0, stream>>>(obs, enc, obs_bf, enc_bf,
                                          obs_nrm, obs_sum, enc_nrm, enc_sum, out);
    pair_kernel<<<4096, 64, 0, stream>>>(obs_bf, enc_bf,
                                         obs_nrm, obs_sum, enc_nrm, enc_sum, out);
}

// Round 2
// 46.966 us; speedup vs baseline: 1.6818x; 1.6818x over previous
//
#include <hip/hip_runtime.h>

#define N 4096
#define D_OBS 64
#define D_ENC 128

typedef short short8 __attribute__((ext_vector_type(8)));
typedef float f32x4 __attribute__((ext_vector_type(4)));

__device__ __forceinline__ unsigned short f2bf(float x) {
    union { float f; unsigned u; } v; v.f = x;
    unsigned r = v.u + 0x7fffu + ((v.u >> 16) & 1u);   // RNE
    return (unsigned short)(r >> 16);
}

// Kernel 1: one wave per row. bf16 conversion + fp32 row norms / row sums.
__global__ void prep_kernel(const float* __restrict__ obs, const float* __restrict__ enc,
                            unsigned short* __restrict__ obs_bf, unsigned short* __restrict__ enc_bf,
                            float* __restrict__ obs_nrm, float* __restrict__ obs_sum,
                            float* __restrict__ enc_nrm, float* __restrict__ enc_sum) {
    int tid  = threadIdx.x;
    int lane = tid & 63;
    int row  = blockIdx.x * 4 + (tid >> 6);

    float o  = obs[row * D_OBS + lane];
    float e0 = enc[row * D_ENC + lane];
    float e1 = enc[row * D_ENC + 64 + lane];
    obs_bf[row * D_OBS + lane]      = f2bf(o);
    enc_bf[row * D_ENC + lane]      = f2bf(e0);
    enc_bf[row * D_ENC + 64 + lane] = f2bf(e1);

    float so = o,        no = o * o;
    float se = e0 + e1,  ne = e0 * e0 + e1 * e1;
    #pragma unroll
    for (int m = 32; m >= 1; m >>= 1) {
        so += __shfl_xor(so, m);
        no += __shfl_xor(no, m);
        se += __shfl_xor(se, m);
        ne += __shfl_xor(ne, m);
    }
    if (lane == 0) {
        obs_sum[row] = so; obs_nrm[row] = no;
        enc_sum[row] = se; enc_nrm[row] = ne;
    }
}

// Kernel 2: one wave per 64x64 pair tile. Dual gram (obs K=64, enc K=128) via
// mfma_f32_16x16x32_bf16, fused epilogue, wave reduce, ONE STORE per block
// (no atomics — 4096 same-address atomicAdds serialized ~80us in R1).
__global__ __launch_bounds__(64) void pair_kernel(
    const unsigned short* __restrict__ obs_bf, const unsigned short* __restrict__ enc_bf,
    const float* __restrict__ obs_nrm, const float* __restrict__ obs_sum,
    const float* __restrict__ enc_nrm, const float* __restrict__ enc_sum,
    float* __restrict__ partials)
{
    const float EPSV   = 1e-6f;
    const float floorO = (float)D_OBS * 1e-12f;   // 6.4e-11
    const float floorE = (float)D_ENC * 1e-12f;   // 1.28e-10

    int l  = threadIdx.x;
    int bi = blockIdx.x & 63, bj = blockIdx.x >> 6;
    int I0 = bi * 64, J0 = bj * 64;
    int lr = l & 15;           // fragment row/col within 16
    int lk = (l >> 4) * 8;     // k offset within 32-K step

    const unsigned short* aObs = obs_bf + (size_t)(I0 + lr) * D_OBS + lk;
    const unsigned short* bObs = obs_bf + (size_t)(J0 + lr) * D_OBS + lk;
    const unsigned short* aEnc = enc_bf + (size_t)(I0 + lr) * D_ENC + lk;
    const unsigned short* bEnc = enc_bf + (size_t)(J0 + lr) * D_ENC + lk;

    f32x4 accO[4][4], accE[4][4];
    #pragma unroll
    for (int r = 0; r < 4; r++)
        #pragma unroll
        for (int c = 0; c < 4; c++) {
            accO[r][c] = (f32x4){0.f, 0.f, 0.f, 0.f};
            accE[r][c] = (f32x4){0.f, 0.f, 0.f, 0.f};
        }

    #pragma unroll
    for (int ks = 0; ks < 2; ks++) {               // obs gram, K=64
        short8 a[4], b[4];
        #pragma unroll
        for (int r = 0; r < 4; r++) a[r] = *(const short8*)(aObs + r * 16 * D_OBS + ks * 32);
        #pragma unroll
        for (int c = 0; c < 4; c++) b[c] = *(const short8*)(bObs + c * 16 * D_OBS + ks * 32);
        #pragma unroll
        for (int r = 0; r < 4; r++)
            #pragma unroll
            for (int c = 0; c < 4; c++)
                accO[r][c] = __builtin_amdgcn_mfma_f32_16x16x32_bf16(a[r], b[c], accO[r][c], 0, 0, 0);
    }
    #pragma unroll
    for (int ks = 0; ks < 4; ks++) {               // enc gram, K=128
        short8 a[4], b[4];
        #pragma unroll
        for (int r = 0; r < 4; r++) a[r] = *(const short8*)(aEnc + r * 16 * D_ENC + ks * 32);
        #pragma unroll
        for (int c = 0; c < 4; c++) b[c] = *(const short8*)(bEnc + c * 16 * D_ENC + ks * 32);
        #pragma unroll
        for (int r = 0; r < 4; r++)
            #pragma unroll
            for (int c = 0; c < 4; c++)
                accE[r][c] = __builtin_amdgcn_mfma_f32_16x16x32_bf16(a[r], b[c], accE[r][c], 0, 0, 0);
    }

    // j-side norms preload (4 per array, indexed by c)
    float jn_no[4], jn_so[4], jn_ne[4], jn_se[4];
    #pragma unroll
    for (int c = 0; c < 4; c++) {
        int j = J0 + c * 16 + lr;
        jn_no[c] = obs_nrm[j]; jn_so[c] = obs_sum[j];
        jn_ne[c] = enc_nrm[j]; jn_se[c] = enc_sum[j];
    }

    float lsum = 0.0f;
    int rq = (l >> 4) * 4;
    #pragma unroll
    for (int r = 0; r < 4; r++) {
        #pragma unroll
        for (int q = 0; q < 4; q++) {
            int i = I0 + r * 16 + rq + q;
            float no_i = obs_nrm[i], so_i = obs_sum[i];
            float ne_i = enc_nrm[i], se_i = enc_sum[i];
            #pragma unroll
            for (int c = 0; c < 4; c++) {
                int j = J0 + c * 16 + lr;
                float dob = accO[r][c][q];
                float den = accE[r][c][q];
                // obs squared distance (clamped) -> negative mask
                float sqo = no_i + jn_no[c] - 2.0f * dob
                          + 2.0f * EPSV * (so_i - jn_so[c]) + floorO;
                sqo = fmaxf(sqo, floorO);
                bool neg = sqo > 1e-4f;            // obs_dist > 0.01
                // enc distance
                float sqe = ne_i + jn_ne[c] - 2.0f * den
                          + 2.0f * EPSV * (se_i - jn_se[c]) + floorE;
                float de = sqrtf(fmaxf(sqe, floorE));
                float contrib = neg ? fmaxf(1.0f - de, 0.0f) : (1.0f + de);
                if (i == j) contrib = 1.0f + 1.13137085e-05f;  // exact: 1 + EPS*sqrt(128)
                lsum += contrib;
            }
        }
    }

    #pragma unroll
    for (int m = 32; m >= 1; m >>= 1) lsum += __shfl_xor(lsum, m);
    if (l == 0) partials[blockIdx.x] = lsum * (1.0f / 16777216.0f);  // /N^2
}

// Kernel 3: single block, reduce 4096 partials -> out[0].
__global__ __launch_bounds__(1024) void reduce_kernel(const float* __restrict__ part,
                                                      float* __restrict__ out) {
    __shared__ float s[16];
    int t = threadIdx.x;
    float v = part[t] + part[t + 1024] + part[t + 2048] + part[t + 3072];
    #pragma unroll
    for (int m = 32; m >= 1; m >>= 1) v += __shfl_xor(v, m);
    if ((t & 63) == 0) s[t >> 6] = v;
    __syncthreads();
    if (t < 16) {
        float w = s[t];
        #pragma unroll
        for (int m = 8; m >= 1; m >>= 1) w += __shfl_xor(w, m);
        if (t == 0) out[0] = w;
    }
}

extern "C" void kernel_launch(void* const* d_in, const int* in_sizes, int n_in,
                              void* d_out, int out_size, void* d_ws, size_t ws_size,
                              hipStream_t stream) {
    const float* obs = (const float*)d_in[0];
    const float* enc = (const float*)d_in[1];
    float* out = (float*)d_out;

    char* ws = (char*)d_ws;
    unsigned short* obs_bf = (unsigned short*)(ws + 0);          // 512 KiB
    unsigned short* enc_bf = (unsigned short*)(ws + 524288);     // 1 MiB
    float* obs_nrm = (float*)(ws + 1572864);
    float* obs_sum = (float*)(ws + 1589248);
    float* enc_nrm = (float*)(ws + 1605632);
    float* enc_sum = (float*)(ws + 1622016);
    float* partials = (float*)(ws + 1638400);                    // 16 KiB

    prep_kernel<<<1024, 256, 0, stream>>>(obs, enc, obs_bf, enc_bf,
                                          obs_nrm, obs_sum, enc_nrm, enc_sum);
    pair_kernel<<<4096, 64, 0, stream>>>(obs_bf, enc_bf,
                                         obs_nrm, obs_sum, enc_nrm, enc_sum, partials);
    reduce_kernel<<<1, 1024, 0, stream>>>(partials, out);
}